// Round 10
// baseline (505.398 us; speedup 1.0000x reference)
//
#include <hip/hip_runtime.h>
#include <math.h>

#define OS    320      // oversampled grid (ceil(1.25*256))
#define IMN   256
#define NCOIL 8
#define HS    326      // halo grid dim (3-cell wrap halo each side)
#define HROWB (HS * 32)   // halo row stride in bytes (cell = 32B)
#define PI_F  3.14159265358979f
#define BETA_F 10.955108f   // pi*sqrt((4.8*0.75)^2 - 0.8)
#define GSCALE 65536.0f     // fp16 grid scaling

// binning
#define TILE  16
#define BX    20
#define NBINS 400
#define CHUNK 512
#define NCHUNK 8
#define RS    23               // region row stride in cells (pad 22->23)
#define RROWB (RS * 32)        // 736 B
#define REGROWS 22

typedef _Float16 half8  __attribute__((ext_vector_type(8)));
typedef _Float16 half4  __attribute__((ext_vector_type(4)));
typedef unsigned uint2v __attribute__((ext_vector_type(2)));

// f32 acc += f32 w * f16 (lo/hi half of dword h)   [validated r6/r8]
__device__ __forceinline__ void fmamix_lo(float& acc, float w, unsigned h) {
    asm("v_fma_mix_f32 %0, %1, %2, %0 op_sel_hi:[0,1,0]"
        : "+v"(acc) : "v"(w), "v"(h));
}
__device__ __forceinline__ void fmamix_hi(float& acc, float w, unsigned h) {
    asm("v_fma_mix_f32 %0, %1, %2, %0 op_sel:[0,1,0] op_sel_hi:[0,1,0]"
        : "+v"(acc) : "v"(w), "v"(h));
}

// ---- Kaiser-Bessel: exact A&S I0 polynomial (matches reference) ----
__device__ __forceinline__ float i0f(float x) {
    if (x < 3.75f) {
        float y = x * (1.0f / 3.75f); y *= y;
        return 1.0f + y*(3.5156229f + y*(3.0899424f + y*(1.2067492f
             + y*(0.2659732f + y*(0.0360768f + y*0.0045813f)))));
    } else {
        float t = 3.75f / x;
        float p = 0.39894228f + t*(0.01328592f + t*(0.00225319f + t*(-0.00157565f
              + t*(0.00916281f + t*(-0.02057706f + t*(0.02635537f + t*(-0.01647633f
              + t*0.00392377f)))))));
        return expf(x) * rsqrtf(x) * p;
    }
}

__device__ __forceinline__ float apod1(int i) {
    float idx = (float)(i - 128);
    float c = PI_F * 6.0f * idx * (1.0f / (float)OS);
    float a = sqrtf(BETA_F * BETA_F - c * c);
    float sh = 0.5f * (expf(a) - expf(-a));
    return a / sh;
}

__device__ __forceinline__ int bin_of(float2 tj) {
    float cy = tj.x * 1.25f + 160.0f;
    float cx = tj.y * 1.25f + 160.0f;
    int by = (int)cy >> 4; by = by < 0 ? 0 : (by > 19 ? 19 : by);
    int bx = (int)cx >> 4; bx = bx < 0 ? 0 : (bx > 19 ? 19 : bx);
    return by * BX + bx;
}

// ---- K0: weight LUT + hist zero.  lut[i] = I0(beta*sqrt(1 - i/1024)) ----
__global__ void build_lut(float* __restrict__ lut, unsigned* __restrict__ hist) {
    int i = blockIdx.x * 256 + threadIdx.x;
    if (i <= 1024)
        lut[i] = i0f(BETA_F * sqrtf(1.0f - (float)i * (1.0f / 1024.0f)));
    if (blockIdx.x == 0)
        for (int j = threadIdx.x; j < NBINS; j += 256) hist[j] = 0;
}

// ---- K1: fused apod + pad + DFT along x (coil-split x2) [unchanged r8] ----
__global__ __launch_bounds__(320) void dft_pass1(const float* __restrict__ imr,
                                                 const float* __restrict__ imi,
                                                 float2* __restrict__ out) {
    __shared__ float2 xs[IMN * 4];
    int iy = blockIdx.x;
    int c0 = blockIdx.y * 4;
    int t  = threadIdx.x;                // kx
    if (t < IMN) {
        float ap = apod1(t);
        int base = iy * IMN + t;
        #pragma unroll
        for (int b = 0; b < 4; ++b) {
            float xr = imr[(c0 + b) * (IMN * IMN) + base];
            float xi = imi[(c0 + b) * (IMN * IMN) + base];
            xs[t * 4 + b] = make_float2(xr * ap, xi * ap);
        }
    }
    __syncthreads();

    float ar[4], ai[4];
    #pragma unroll
    for (int b = 0; b < 4; ++b) { ar[b] = 0.f; ai[b] = 0.f; }
    float ang_t = (float)t * (-2.0f * PI_F / (float)OS);
    float wsr = cosf(ang_t), wsi = sinf(ang_t);
    int idx = (t * 192) % 320;
    float wr = 1.f, wi = 0.f;
    const float4* xv = (const float4*)xs;
    #pragma unroll 16
    for (int m = 0; m < 256; ++m) {
        if ((m & 15) == 0) {
            float ang = (float)idx * (-2.0f * PI_F / (float)OS);
            wr = cosf(ang); wi = sinf(ang);
        }
        const float4* xp = xv + m * 2;
        #pragma unroll
        for (int q = 0; q < 2; ++q) {
            float4 x = xp[q];
            ar[2*q]   = fmaf(x.x, wr, fmaf(-x.y, wi, ar[2*q]));
            ai[2*q]   = fmaf(x.x, wi, fmaf( x.y, wr, ai[2*q]));
            ar[2*q+1] = fmaf(x.z, wr, fmaf(-x.w, wi, ar[2*q+1]));
            ai[2*q+1] = fmaf(x.z, wi, fmaf( x.w, wr, ai[2*q+1]));
        }
        float nwr = fmaf(wr, wsr, -wi * wsi);
        float nwi = fmaf(wr, wsi,  wi * wsr);
        wr = nwr; wi = nwi;
        idx += t; if (idx >= OS) idx -= OS;
    }
    float ay = apod1(iy) * (1.0f / 256.0f);
    int y = iy + 192; if (y >= OS) y -= OS;
    float4* op = (float4*)(out + ((size_t)t * OS + y) * NCOIL + c0);
    op[0] = make_float4(ar[0] * ay, ai[0] * ay, ar[1] * ay, ai[1] * ay);
    op[1] = make_float4(ar[2] * ay, ai[2] * ay, ar[3] * ay, ai[3] * ay);
}

// ---- K2: DFT along y (coil-split); fp16 HALO grid out [unchanged r8] ----
__global__ __launch_bounds__(320) void dft_pass2(const float2* __restrict__ in,
                                                 char* __restrict__ gbytes) {
    __shared__ float2 xs[IMN * 4];
    int kx = blockIdx.x;
    int c0 = blockIdx.y * 4;
    int t  = threadIdx.x;
    const float2* row = in + (size_t)kx * OS * NCOIL + c0;
    for (int i = t; i < IMN * 4; i += 320) {
        int m = i >> 2, b = i & 3;
        int n = m + 192; if (n >= OS) n -= OS;
        xs[i] = row[n * NCOIL + b];
    }
    __syncthreads();

    float ar[4], ai[4];
    #pragma unroll
    for (int b = 0; b < 4; ++b) { ar[b] = 0.f; ai[b] = 0.f; }
    float ang_t = (float)t * (-2.0f * PI_F / (float)OS);
    float wsr = cosf(ang_t), wsi = sinf(ang_t);
    int idx = (t * 192) % 320;
    float wr = 1.f, wi = 0.f;
    const float4* xv = (const float4*)xs;
    #pragma unroll 16
    for (int m = 0; m < 256; ++m) {
        if ((m & 15) == 0) {
            float ang = (float)idx * (-2.0f * PI_F / (float)OS);
            wr = cosf(ang); wi = sinf(ang);
        }
        const float4* xp = xv + m * 2;
        #pragma unroll
        for (int q = 0; q < 2; ++q) {
            float4 x = xp[q];
            ar[2*q]   = fmaf(x.x, wr, fmaf(-x.y, wi, ar[2*q]));
            ai[2*q]   = fmaf(x.x, wi, fmaf( x.y, wr, ai[2*q]));
            ar[2*q+1] = fmaf(x.z, wr, fmaf(-x.w, wi, ar[2*q+1]));
            ai[2*q+1] = fmaf(x.z, wi, fmaf( x.w, wr, ai[2*q+1]));
        }
        float nwr = fmaf(wr, wsr, -wi * wsi);
        float nwi = fmaf(wr, wsi,  wi * wsr);
        wr = nwr; wi = nwi;
        idx += t; if (idx >= OS) idx -= OS;
    }
    int r = t + 160;  if (r >= OS) r -= OS;
    int c = kx + 160; if (c >= OS) c -= OS;
    half8 hh;
    #pragma unroll
    for (int q = 0; q < 4; ++q) {
        hh[2*q]   = (_Float16)(ar[q] * GSCALE);
        hh[2*q+1] = (_Float16)(ai[q] * GSCALE);
    }
    int hys[2]; int nhy = 1; hys[0] = r + 3;
    if (r < 3)        hys[nhy++] = r + 323;
    else if (r >= 317) hys[nhy++] = r - 317;
    int hxs[2]; int nhx = 1; hxs[0] = c + 3;
    if (c < 3)        hxs[nhx++] = c + 323;
    else if (c >= 317) hxs[nhx++] = c - 317;
    for (int a = 0; a < nhy; ++a)
        for (int b = 0; b < nhx; ++b)
            *(half8*)(gbytes + (size_t)hys[a] * HROWB + hxs[b] * 32 + c0 * 4) = hh;
}

// ---- sort: histogram -> scan -> scatter ----
__global__ __launch_bounds__(256) void hist_kernel(const float* __restrict__ trj,
                                                   unsigned* __restrict__ hist, int K) {
    __shared__ unsigned lh[NBINS];
    for (int i = threadIdx.x; i < NBINS; i += 256) lh[i] = 0;
    __syncthreads();
    int stride = gridDim.x * 256;
    const float2* trj2 = (const float2*)trj;
    for (int k = blockIdx.x * 256 + threadIdx.x; k < K; k += stride)
        atomicAdd(&lh[bin_of(trj2[k])], 1u);
    __syncthreads();
    for (int i = threadIdx.x; i < NBINS; i += 256)
        if (lh[i]) atomicAdd(&hist[i], lh[i]);
}

__global__ __launch_bounds__(512) void scan_kernel(const unsigned* __restrict__ hist,
                                                   unsigned* __restrict__ bases,
                                                   unsigned* __restrict__ cursor) {
    __shared__ unsigned a[512], b[512];
    int i = threadIdx.x;
    a[i] = (i < NBINS) ? hist[i] : 0;
    __syncthreads();                       // FIX r9->r10: cross-wave race
    unsigned *src = a, *dst = b;
    for (int off = 1; off < 512; off <<= 1) {
        dst[i] = src[i] + ((i >= off) ? src[i - off] : 0);
        __syncthreads();
        unsigned* t = src; src = dst; dst = t;
    }
    if (i < NBINS) {
        bases[i + 1] = src[i];
        cursor[i] = (i == 0) ? 0u : src[i - 1];
        if (i == 0) bases[0] = 0;
    }
}

__global__ __launch_bounds__(256) void scatter_kernel(const float* __restrict__ trj,
                                                      unsigned* __restrict__ cursor,
                                                      unsigned* __restrict__ sidx, int K) {
    __shared__ unsigned short lbin[2048];
    __shared__ unsigned lcnt[NBINS], lbase[NBINS], lcur[NBINS];
    for (int i = threadIdx.x; i < NBINS; i += 256) { lcnt[i] = 0; lcur[i] = 0; }
    __syncthreads();
    int base = blockIdx.x * 2048;
    const float2* trj2 = (const float2*)trj;
    #pragma unroll
    for (int j = 0; j < 8; ++j) {
        int idx = threadIdx.x + j * 256;
        int k = base + idx;
        if (k < K) {
            int b = bin_of(trj2[k]);
            lbin[idx] = (unsigned short)b;
            atomicAdd(&lcnt[b], 1u);
        }
    }
    __syncthreads();
    for (int i = threadIdx.x; i < NBINS; i += 256)
        if (lcnt[i]) lbase[i] = atomicAdd(&cursor[i], lcnt[i]);
    __syncthreads();
    #pragma unroll
    for (int j = 0; j < 8; ++j) {
        int idx = threadIdx.x + j * 256;
        int k = base + idx;
        if (k < K) {
            int b = lbin[idx];
            unsigned off = atomicAdd(&lcur[b], 1u);
            sidx[lbase[b] + off] = (unsigned)k;
        }
    }
}

// ---- K3: binned KB 6x6 gather. Block = (bin, chunk); stage the bin's
// 22x22-cell halo region into LDS once, then all 36 taps are LDS reads.
// 8 lanes/point = 4 coil-pairs x 2 tap-parities (r8 structure).
__global__ __launch_bounds__(256) void interp_binned(
        const float* __restrict__ trj, const char* __restrict__ gbytes,
        const float* __restrict__ lut, const unsigned* __restrict__ sidx,
        const unsigned* __restrict__ bases, float2* __restrict__ out, int K) {
    __shared__ char reg[REGROWS * RROWB];   // 16,192 B
    int bid = blockIdx.x;
    int bin = bid >> 3, ch = bid & (NCHUNK - 1);
    unsigned bstart = bases[bin], bend = bases[bin + 1];
    unsigned pstart = bstart + (unsigned)ch * CHUNK;
    if (pstart >= bend) return;
    unsigned pstop = (ch == NCHUNK - 1) ? bend : min(bend, pstart + CHUNK);

    int by = bin / BX, bx = bin % BX;
    const char* src = gbytes + (size_t)(by * TILE) * HROWB + (bx * TILE) * 32;
    for (int f = threadIdx.x; f < REGROWS * 44; f += 256) {
        int rr = f / 44, cc = f % 44;      // 44 float4 per 704B row
        *(float4*)(reg + rr * RROWB + cc * 16) =
            *(const float4*)(src + (size_t)rr * HROWB + cc * 16);
    }
    __syncthreads();

    int grp = threadIdx.x >> 3;
    int c   = threadIdx.x & 7;
    int cp  = c & 3;            // coil pair
    int tp  = c >> 2;           // tap parity
    int gb  = (threadIdx.x & 63) & 56;
    const float2* trj2 = (const float2*)trj;
    int ybase = by * TILE - 3;  // logical y of region row 0
    int xbase = bx * TILE - 3;

    for (unsigned spos = pstart + grp; spos < pstop; spos += 32) {
        unsigned k = sidx[spos];
        float2 tj = trj2[k];
        float cy = tj.x * 1.25f + 160.0f;
        float cx = tj.y * 1.25f + 160.0f;
        int y0 = (int)ceilf(cy - 3.0f);
        int x0 = (int)ceilf(cx - 3.0f);
        int ry0 = y0 - ybase;   // in [0,16]
        int rx0 = x0 - xbase;
        const char* base0 = reg + ry0 * RROWB + rx0 * 32 + cp * 8 + tp * 32;

        half4 h[18];
        #pragma unroll
        for (int j = 0; j < 6; ++j) {
            const char* rb = base0 + j * RROWB;
            #pragma unroll
            for (int p = 0; p < 3; ++p)
                h[j * 3 + p] = *(const half4*)(rb + p * 64);
        }

        float argu = (c < 6) ? ((float)(y0 + c) - cy) * (1.0f / 3.0f)
                             : ((float)(x0 + (c - 6)) - cx) * (1.0f / 3.0f);
        float argv = ((float)(x0 + 2 + cp) - cx) * (1.0f / 3.0f);
        float tu = fminf(argu * argu * 1024.0f, 1023.0f);
        int   iu = (int)tu;  float fu = tu - (float)iu;
        float a0 = lut[iu], a1 = lut[iu + 1];
        float u = fmaf(fu, a1 - a0, a0);
        float tv = fminf(argv * argv * 1024.0f, 1023.0f);
        int   iv = (int)tv;  float fv = tv - (float)iv;
        float b0 = lut[iv], b1 = lut[iv + 1];
        float v = fmaf(fv, b1 - b0, b0);

        float wy[6], wx[6];
        wy[0] = __shfl(u, gb + 0); wy[1] = __shfl(u, gb + 1);
        wy[2] = __shfl(u, gb + 2); wy[3] = __shfl(u, gb + 3);
        wy[4] = __shfl(u, gb + 4); wy[5] = __shfl(u, gb + 5);
        wx[0] = __shfl(u, gb + 6); wx[1] = __shfl(u, gb + 7);
        wx[2] = __shfl(v, gb + 0); wx[3] = __shfl(v, gb + 1);
        wx[4] = __shfl(v, gb + 2); wx[5] = __shfl(v, gb + 3);

        float accr0 = 0.f, acci0 = 0.f, accr1 = 0.f, acci1 = 0.f;
        #pragma unroll
        for (int j = 0; j < 6; ++j) {
            float wyj = wy[j];
            #pragma unroll
            for (int p = 0; p < 3; ++p) {
                float w = wyj * wx[2 * p + tp];
                uint2v hu = __builtin_bit_cast(uint2v, h[j * 3 + p]);
                fmamix_lo(accr0, w, hu.x);
                fmamix_hi(acci0, w, hu.x);
                fmamix_lo(accr1, w, hu.y);
                fmamix_hi(acci1, w, hu.y);
            }
        }
        accr0 += __shfl_xor(accr0, 4);
        acci0 += __shfl_xor(acci0, 4);
        accr1 += __shfl_xor(accr1, 4);
        acci1 += __shfl_xor(acci1, 4);

        const float s = 1.0f / (36.0f * GSCALE);
        float2 res = tp ? make_float2(accr1 * s, acci1 * s)
                        : make_float2(accr0 * s, acci0 * s);
        union { float2 f; double d; } ru; ru.f = res;
        __builtin_nontemporal_store(ru.d,
            (double*)(out + (size_t)(2 * cp + tp) * K + k));
    }
}

extern "C" void kernel_launch(void* const* d_in, const int* in_sizes, int n_in,
                              void* d_out, int out_size, void* d_ws, size_t ws_size,
                              hipStream_t stream) {
    const float* imr = (const float*)d_in[0];
    const float* imi = (const float*)d_in[1];
    const float* trj = (const float*)d_in[2];
    int K = in_sizes[2] / 2;

    char* ws = (char*)d_ws;
    float2*   buf1  = (float2*)ws;                          // 6,553,600 B
    char*     gridh = ws + 6553600;                         // 3,400,832 B halo
    float*    lut   = (float*)(ws + 9954432);               // 4,100 B
    unsigned* hist  = (unsigned*)(ws + 9958656);            // 1,600 B
    unsigned* bases = (unsigned*)(ws + 9960320);            // 1,604 B
    unsigned* cursor= (unsigned*)(ws + 9961984);            // 1,600 B
    unsigned* sidx  = (unsigned*)buf1;   // aliases buf1 (dead after pass2)

    (void)n_in; (void)out_size; (void)ws_size;

    build_lut<<<5, 256, 0, stream>>>(lut, hist);
    dft_pass1<<<dim3(IMN, 2), 320, 0, stream>>>(imr, imi, buf1);
    dft_pass2<<<dim3(OS, 2), 320, 0, stream>>>(buf1, gridh);
    hist_kernel<<<512, 256, 0, stream>>>(trj, hist, K);
    scan_kernel<<<1, 512, 0, stream>>>(hist, bases, cursor);
    scatter_kernel<<<(K + 2047) / 2048, 256, 0, stream>>>(trj, cursor, sidx, K);
    interp_binned<<<NBINS * NCHUNK, 256, 0, stream>>>(trj, gridh, lut, sidx, bases,
                                                      (float2*)d_out, K);
}

// Round 11
// 252.863 us; speedup vs baseline: 1.9987x; 1.9987x over previous
//
#include <hip/hip_runtime.h>
#include <math.h>

#define OS    320      // oversampled grid (ceil(1.25*256))
#define IMN   256
#define NCOIL 8
#define HS    326      // halo grid dim (3-cell wrap halo each side)
#define HROWB (HS * 32)   // halo row stride in bytes (cell = 32B)
#define PI_F  3.14159265358979f
#define BETA_F 10.955108f   // pi*sqrt((4.8*0.75)^2 - 0.8)
#define GSCALE 65536.0f     // fp16 grid scaling

// binning
#define TILE  16
#define BX    20
#define NBINS 400
#define CHUNK 512
#define NCHUNK 8
#define RS    23               // region row stride in cells (pad 22->23)
#define RROWB (RS * 32)        // 736 B
#define REGROWS 22

// workspace layout (bytes)
#define OFF_GRIDH  6553600UL
#define OFF_LUT    9954432UL
#define OFF_HIST   9958656UL
#define OFF_BASES  9960320UL
#define OFF_CURSOR 9961984UL
#define OFF_STRJ   9965568UL
#define OFF_RANK   18354176UL
#define OFF_TMP    22548480UL
#define WS_NEEDED  56102912UL

typedef _Float16 half8  __attribute__((ext_vector_type(8)));
typedef _Float16 half4  __attribute__((ext_vector_type(4)));
typedef _Float16 half2v __attribute__((ext_vector_type(2)));
typedef unsigned uint2v __attribute__((ext_vector_type(2)));

// f32 acc += f32 w * f16 (lo/hi half of dword h)   [validated r6/r8]
__device__ __forceinline__ void fmamix_lo(float& acc, float w, unsigned h) {
    asm("v_fma_mix_f32 %0, %1, %2, %0 op_sel_hi:[0,1,0]"
        : "+v"(acc) : "v"(w), "v"(h));
}
__device__ __forceinline__ void fmamix_hi(float& acc, float w, unsigned h) {
    asm("v_fma_mix_f32 %0, %1, %2, %0 op_sel:[0,1,0] op_sel_hi:[0,1,0]"
        : "+v"(acc) : "v"(w), "v"(h));
}

__device__ __forceinline__ float2 h2f2(unsigned u) {
    half2v h = __builtin_bit_cast(half2v, u);
    return make_float2((float)h.x, (float)h.y);
}

// ---- Kaiser-Bessel: exact A&S I0 polynomial (matches reference) ----
__device__ __forceinline__ float i0f(float x) {
    if (x < 3.75f) {
        float y = x * (1.0f / 3.75f); y *= y;
        return 1.0f + y*(3.5156229f + y*(3.0899424f + y*(1.2067492f
             + y*(0.2659732f + y*(0.0360768f + y*0.0045813f)))));
    } else {
        float t = 3.75f / x;
        float p = 0.39894228f + t*(0.01328592f + t*(0.00225319f + t*(-0.00157565f
              + t*(0.00916281f + t*(-0.02057706f + t*(0.02635537f + t*(-0.01647633f
              + t*0.00392377f)))))));
        return expf(x) * rsqrtf(x) * p;
    }
}

__device__ __forceinline__ float apod1(int i) {
    float idx = (float)(i - 128);
    float c = PI_F * 6.0f * idx * (1.0f / (float)OS);
    float a = sqrtf(BETA_F * BETA_F - c * c);
    float sh = 0.5f * (expf(a) - expf(-a));
    return a / sh;
}

__device__ __forceinline__ int bin_of(float2 tj) {
    float cy = tj.x * 1.25f + 160.0f;
    float cx = tj.y * 1.25f + 160.0f;
    int by = (int)cy >> 4; by = by < 0 ? 0 : (by > 19 ? 19 : by);
    int bx = (int)cx >> 4; bx = bx < 0 ? 0 : (bx > 19 ? 19 : bx);
    return by * BX + bx;
}

// ---- K0: weight LUT + hist zero ----
__global__ void build_lut(float* __restrict__ lut, unsigned* __restrict__ hist) {
    int i = blockIdx.x * 256 + threadIdx.x;
    if (i <= 1024)
        lut[i] = i0f(BETA_F * sqrtf(1.0f - (float)i * (1.0f / 1024.0f)));
    if (blockIdx.x == 0)
        for (int j = threadIdx.x; j < NBINS; j += 256) hist[j] = 0;
}

// ---- K1: fused apod + pad + DFT along x (coil-split x4: 2 coils/block) ----
__global__ __launch_bounds__(320) void dft_pass1(const float* __restrict__ imr,
                                                 const float* __restrict__ imi,
                                                 float2* __restrict__ out) {
    __shared__ float4 xs[IMN];           // (re0,im0,re1,im1) per m, 4 KB
    int iy = blockIdx.x;
    int c0 = blockIdx.y * 2;
    int t  = threadIdx.x;                // kx
    if (t < IMN) {
        float ap = apod1(t);
        int base = iy * IMN + t;
        xs[t] = make_float4(imr[c0 * (IMN*IMN) + base] * ap,
                            imi[c0 * (IMN*IMN) + base] * ap,
                            imr[(c0+1) * (IMN*IMN) + base] * ap,
                            imi[(c0+1) * (IMN*IMN) + base] * ap);
    }
    __syncthreads();

    float ar0 = 0.f, ai0 = 0.f, ar1 = 0.f, ai1 = 0.f;
    float ang_t = (float)t * (-2.0f * PI_F / (float)OS);
    float wsr = cosf(ang_t), wsi = sinf(ang_t);
    int idx = (t * 192) % 320;           // (t*n) mod 320 at n=192
    float wr = 1.f, wi = 0.f;
    #pragma unroll 16
    for (int m = 0; m < 256; ++m) {
        if ((m & 15) == 0) {             // exact twiddle refresh
            float ang = (float)idx * (-2.0f * PI_F / (float)OS);
            wr = cosf(ang); wi = sinf(ang);
        }
        float4 x = xs[m];                // LDS broadcast
        ar0 = fmaf(x.x, wr, fmaf(-x.y, wi, ar0));
        ai0 = fmaf(x.x, wi, fmaf( x.y, wr, ai0));
        ar1 = fmaf(x.z, wr, fmaf(-x.w, wi, ar1));
        ai1 = fmaf(x.z, wi, fmaf( x.w, wr, ai1));
        float nwr = fmaf(wr, wsr, -wi * wsi);
        float nwi = fmaf(wr, wsi,  wi * wsr);
        wr = nwr; wi = nwi;
        idx += t; if (idx >= OS) idx -= OS;
    }
    float ay = apod1(iy) * (1.0f / 256.0f);
    int y = iy + 192; if (y >= OS) y -= OS;
    *(float4*)(out + ((size_t)t * OS + y) * NCOIL + c0) =
        make_float4(ar0 * ay, ai0 * ay, ar1 * ay, ai1 * ay);
}

// ---- K2: DFT along y (coil-split x4); fp16 HALO grid out, fftshift folded ----
__global__ __launch_bounds__(320) void dft_pass2(const float2* __restrict__ in,
                                                 char* __restrict__ gbytes) {
    __shared__ float2 xs[IMN * 2];
    int kx = blockIdx.x;
    int c0 = blockIdx.y * 2;
    int t  = threadIdx.x;
    const float2* row = in + (size_t)kx * OS * NCOIL + c0;
    for (int i = t; i < IMN * 2; i += 320) {
        int m = i >> 1, b = i & 1;
        int n = m + 192; if (n >= OS) n -= OS;
        xs[i] = row[n * NCOIL + b];
    }
    __syncthreads();

    float ar0 = 0.f, ai0 = 0.f, ar1 = 0.f, ai1 = 0.f;
    float ang_t = (float)t * (-2.0f * PI_F / (float)OS);
    float wsr = cosf(ang_t), wsi = sinf(ang_t);
    int idx = (t * 192) % 320;
    float wr = 1.f, wi = 0.f;
    const float4* xv = (const float4*)xs;
    #pragma unroll 16
    for (int m = 0; m < 256; ++m) {
        if ((m & 15) == 0) {
            float ang = (float)idx * (-2.0f * PI_F / (float)OS);
            wr = cosf(ang); wi = sinf(ang);
        }
        float4 x = xv[m];
        ar0 = fmaf(x.x, wr, fmaf(-x.y, wi, ar0));
        ai0 = fmaf(x.x, wi, fmaf( x.y, wr, ai0));
        ar1 = fmaf(x.z, wr, fmaf(-x.w, wi, ar1));
        ai1 = fmaf(x.z, wi, fmaf( x.w, wr, ai1));
        float nwr = fmaf(wr, wsr, -wi * wsi);
        float nwi = fmaf(wr, wsi,  wi * wsr);
        wr = nwr; wi = nwi;
        idx += t; if (idx >= OS) idx -= OS;
    }
    int r = t + 160;  if (r >= OS) r -= OS;   // fftshift fold (rows)
    int c = kx + 160; if (c >= OS) c -= OS;   // fftshift fold (cols)
    half4 hh;
    hh[0] = (_Float16)(ar0 * GSCALE); hh[1] = (_Float16)(ai0 * GSCALE);
    hh[2] = (_Float16)(ar1 * GSCALE); hh[3] = (_Float16)(ai1 * GSCALE);
    int hys[2]; int nhy = 1; hys[0] = r + 3;
    if (r < 3)        hys[nhy++] = r + 323;
    else if (r >= 317) hys[nhy++] = r - 317;
    int hxs[2]; int nhx = 1; hxs[0] = c + 3;
    if (c < 3)        hxs[nhx++] = c + 323;
    else if (c >= 317) hxs[nhx++] = c - 317;
    for (int a = 0; a < nhy; ++a)
        for (int b = 0; b < nhx; ++b)
            *(half4*)(gbytes + (size_t)hys[a] * HROWB + hxs[b] * 32 + c0 * 4) = hh;
}

// ---- sort: histogram -> scan -> scatter(coords + rank) ----
__global__ __launch_bounds__(256) void hist_kernel(const float* __restrict__ trj,
                                                   unsigned* __restrict__ hist, int K) {
    __shared__ unsigned lh[NBINS];
    for (int i = threadIdx.x; i < NBINS; i += 256) lh[i] = 0;
    __syncthreads();
    int stride = gridDim.x * 256;
    const float2* trj2 = (const float2*)trj;
    for (int k = blockIdx.x * 256 + threadIdx.x; k < K; k += stride)
        atomicAdd(&lh[bin_of(trj2[k])], 1u);
    __syncthreads();
    for (int i = threadIdx.x; i < NBINS; i += 256)
        if (lh[i]) atomicAdd(&hist[i], lh[i]);
}

__global__ __launch_bounds__(512) void scan_kernel(const unsigned* __restrict__ hist,
                                                   unsigned* __restrict__ bases,
                                                   unsigned* __restrict__ cursor) {
    __shared__ unsigned a[512], b[512];
    int i = threadIdx.x;
    a[i] = (i < NBINS) ? hist[i] : 0;
    __syncthreads();                       // cross-wave race fix (r10)
    unsigned *src = a, *dst = b;
    for (int off = 1; off < 512; off <<= 1) {
        dst[i] = src[i] + ((i >= off) ? src[i - off] : 0);
        __syncthreads();
        unsigned* t = src; src = dst; dst = t;
    }
    if (i < NBINS) {
        bases[i + 1] = src[i];
        cursor[i] = (i == 0) ? 0u : src[i - 1];
        if (i == 0) bases[0] = 0;
    }
}

__global__ __launch_bounds__(256) void scatter_kernel(const float* __restrict__ trj,
                                                      unsigned* __restrict__ cursor,
                                                      float2* __restrict__ strj,
                                                      unsigned* __restrict__ rank, int K) {
    __shared__ unsigned short lbin[2048];
    __shared__ unsigned lcnt[NBINS], lbase[NBINS], lcur[NBINS];
    for (int i = threadIdx.x; i < NBINS; i += 256) { lcnt[i] = 0; lcur[i] = 0; }
    __syncthreads();
    int base = blockIdx.x * 2048;
    const float2* trj2 = (const float2*)trj;
    float2 tjr[8];
    #pragma unroll
    for (int j = 0; j < 8; ++j) {
        int idx = threadIdx.x + j * 256;
        int k = base + idx;
        if (k < K) {
            tjr[j] = trj2[k];
            int b = bin_of(tjr[j]);
            lbin[idx] = (unsigned short)b;
            atomicAdd(&lcnt[b], 1u);
        }
    }
    __syncthreads();
    for (int i = threadIdx.x; i < NBINS; i += 256)
        if (lcnt[i]) lbase[i] = atomicAdd(&cursor[i], lcnt[i]);
    __syncthreads();
    #pragma unroll
    for (int j = 0; j < 8; ++j) {
        int idx = threadIdx.x + j * 256;
        int k = base + idx;
        if (k < K) {
            int b = lbin[idx];
            unsigned off = atomicAdd(&lcur[b], 1u);
            unsigned spos = lbase[b] + off;
            strj[spos] = tjr[j];           // coords into sorted order
            rank[k] = spos;                // inverse perm, coalesced by k
        }
    }
}

// ---- K3: binned KB 6x6 gather — fully streaming. Reads strj sequentially,
// taps from the LDS-staged 22x22 region, writes fp16 8-coil cell to tmp[spos]
// (coalesced). No random access anywhere.
__global__ __launch_bounds__(256) void interp_binned(
        const float2* __restrict__ strj, const char* __restrict__ gbytes,
        const float* __restrict__ lut, const unsigned* __restrict__ bases,
        char* __restrict__ tmpb) {
    __shared__ char reg[REGROWS * RROWB];   // 16,192 B
    int bid = blockIdx.x;
    int bin = bid >> 3, ch = bid & (NCHUNK - 1);
    unsigned bstart = bases[bin], bend = bases[bin + 1];
    unsigned pstart = bstart + (unsigned)ch * CHUNK;
    if (pstart >= bend) return;
    unsigned pstop = (ch == NCHUNK - 1) ? bend : min(bend, pstart + CHUNK);

    int by = bin / BX, bx = bin % BX;
    const char* src = gbytes + (size_t)(by * TILE) * HROWB + (bx * TILE) * 32;
    for (int f = threadIdx.x; f < REGROWS * 44; f += 256) {
        int rr = f / 44, cc = f % 44;
        *(float4*)(reg + rr * RROWB + cc * 16) =
            *(const float4*)(src + (size_t)rr * HROWB + cc * 16);
    }
    __syncthreads();

    int grp = threadIdx.x >> 3;
    int c   = threadIdx.x & 7;
    int cp  = c & 3;            // coil pair
    int tp  = c >> 2;           // tap parity
    int gb  = (threadIdx.x & 63) & 56;
    int ybase = by * TILE - 3;
    int xbase = bx * TILE - 3;

    for (unsigned spos = pstart + grp; spos < pstop; spos += 32) {
        float2 tj = strj[spos];            // sequential (sorted) read
        float cy = tj.x * 1.25f + 160.0f;
        float cx = tj.y * 1.25f + 160.0f;
        int y0 = (int)ceilf(cy - 3.0f);
        int x0 = (int)ceilf(cx - 3.0f);
        int ry0 = y0 - ybase;
        int rx0 = x0 - xbase;
        const char* base0 = reg + ry0 * RROWB + rx0 * 32 + cp * 8 + tp * 32;

        half4 h[18];
        #pragma unroll
        for (int j = 0; j < 6; ++j) {
            const char* rb = base0 + j * RROWB;
            #pragma unroll
            for (int p = 0; p < 3; ++p)
                h[j * 3 + p] = *(const half4*)(rb + p * 64);
        }

        float argu = (c < 6) ? ((float)(y0 + c) - cy) * (1.0f / 3.0f)
                             : ((float)(x0 + (c - 6)) - cx) * (1.0f / 3.0f);
        float argv = ((float)(x0 + 2 + cp) - cx) * (1.0f / 3.0f);
        float tu = fminf(argu * argu * 1024.0f, 1023.0f);
        int   iu = (int)tu;  float fu = tu - (float)iu;
        float a0 = lut[iu], a1 = lut[iu + 1];
        float u = fmaf(fu, a1 - a0, a0);
        float tv = fminf(argv * argv * 1024.0f, 1023.0f);
        int   iv = (int)tv;  float fv = tv - (float)iv;
        float b0 = lut[iv], b1 = lut[iv + 1];
        float v = fmaf(fv, b1 - b0, b0);

        float wy[6], wx[6];
        wy[0] = __shfl(u, gb + 0); wy[1] = __shfl(u, gb + 1);
        wy[2] = __shfl(u, gb + 2); wy[3] = __shfl(u, gb + 3);
        wy[4] = __shfl(u, gb + 4); wy[5] = __shfl(u, gb + 5);
        wx[0] = __shfl(u, gb + 6); wx[1] = __shfl(u, gb + 7);
        wx[2] = __shfl(v, gb + 0); wx[3] = __shfl(v, gb + 1);
        wx[4] = __shfl(v, gb + 2); wx[5] = __shfl(v, gb + 3);

        float accr0 = 0.f, acci0 = 0.f, accr1 = 0.f, acci1 = 0.f;
        #pragma unroll
        for (int j = 0; j < 6; ++j) {
            float wyj = wy[j];
            #pragma unroll
            for (int p = 0; p < 3; ++p) {
                float w = wyj * wx[2 * p + tp];
                uint2v hu = __builtin_bit_cast(uint2v, h[j * 3 + p]);
                fmamix_lo(accr0, w, hu.x);
                fmamix_hi(acci0, w, hu.x);
                fmamix_lo(accr1, w, hu.y);
                fmamix_hi(acci1, w, hu.y);
            }
        }
        accr0 += __shfl_xor(accr0, 4);
        acci0 += __shfl_xor(acci0, 4);
        accr1 += __shfl_xor(accr1, 4);
        acci1 += __shfl_xor(acci1, 4);

        const float s = 1.0f / (36.0f * GSCALE);
        float rr = (tp ? accr1 : accr0) * s;
        float ri = (tp ? acci1 : acci0) * s;
        half2v hh; hh.x = (_Float16)rr; hh.y = (_Float16)ri;
        // lane's coil = 2cp+tp; 8 lanes fill the 32B cell contiguously
        __builtin_nontemporal_store(__builtin_bit_cast(unsigned, hh),
            (unsigned*)(tmpb + (size_t)spos * 32 + (2 * cp + tp) * 4));
    }
}

// ---- K4: permute tmp (sorted order) -> out (original order) ----
// 1 random 32B read/point; all writes coalesced NT streams.
__global__ __launch_bounds__(256) void permute_out(const unsigned* __restrict__ rank,
                                                   const char* __restrict__ tmpb,
                                                   float2* __restrict__ out, int K) {
    int k = blockIdx.x * 256 + threadIdx.x;
    if (k >= K) return;
    unsigned r = rank[k];
    const uint4* cell = (const uint4*)(tmpb + (size_t)r * 32);
    uint4 a = cell[0], b = cell[1];
    union { float2 f; double d; } u;
    u.f = h2f2(a.x); __builtin_nontemporal_store(u.d, (double*)(out + 0 * (size_t)K + k));
    u.f = h2f2(a.y); __builtin_nontemporal_store(u.d, (double*)(out + 1 * (size_t)K + k));
    u.f = h2f2(a.z); __builtin_nontemporal_store(u.d, (double*)(out + 2 * (size_t)K + k));
    u.f = h2f2(a.w); __builtin_nontemporal_store(u.d, (double*)(out + 3 * (size_t)K + k));
    u.f = h2f2(b.x); __builtin_nontemporal_store(u.d, (double*)(out + 4 * (size_t)K + k));
    u.f = h2f2(b.y); __builtin_nontemporal_store(u.d, (double*)(out + 5 * (size_t)K + k));
    u.f = h2f2(b.z); __builtin_nontemporal_store(u.d, (double*)(out + 6 * (size_t)K + k));
    u.f = h2f2(b.w); __builtin_nontemporal_store(u.d, (double*)(out + 7 * (size_t)K + k));
}

// ---- fallback (ws too small): r8 unbinned interp, validated at ~115 us ----
__global__ __launch_bounds__(256) void interp_unbinned(const float* __restrict__ trj,
                                                       const char* __restrict__ gbytes,
                                                       const float* __restrict__ lut,
                                                       float2* __restrict__ out, int K) {
    int tid = blockIdx.x * 256 + threadIdx.x;
    int k = tid >> 3;
    int c = tid & 7;
    int cp = c & 3;
    int tp = c >> 2;
    if (k >= K) return;
    float2 tj = ((const float2*)trj)[k];
    float cy = tj.x * 1.25f + 160.0f;
    float cx = tj.y * 1.25f + 160.0f;
    int y0 = (int)ceilf(cy - 3.0f);
    int x0 = (int)ceilf(cx - 3.0f);
    const char* base0 = gbytes + (size_t)(y0 + 3) * HROWB
                      + (x0 + 3) * 32 + cp * 8 + tp * 32;
    half4 h[18];
    #pragma unroll
    for (int j = 0; j < 6; ++j) {
        const char* rb = base0 + j * HROWB;
        #pragma unroll
        for (int p = 0; p < 3; ++p)
            h[j * 3 + p] = *(const half4*)(rb + p * 64);
    }
    float argu = (c < 6) ? ((float)(y0 + c) - cy) * (1.0f / 3.0f)
                         : ((float)(x0 + (c - 6)) - cx) * (1.0f / 3.0f);
    float argv = ((float)(x0 + 2 + cp) - cx) * (1.0f / 3.0f);
    float tu = fminf(argu * argu * 1024.0f, 1023.0f);
    int   iu = (int)tu;  float fu = tu - (float)iu;
    float a0 = lut[iu], a1 = lut[iu + 1];
    float u = fmaf(fu, a1 - a0, a0);
    float tv = fminf(argv * argv * 1024.0f, 1023.0f);
    int   iv = (int)tv;  float fv = tv - (float)iv;
    float b0 = lut[iv], b1 = lut[iv + 1];
    float v = fmaf(fv, b1 - b0, b0);
    int gb = (threadIdx.x & 63) & 56;
    float wy[6], wx[6];
    wy[0] = __shfl(u, gb + 0); wy[1] = __shfl(u, gb + 1);
    wy[2] = __shfl(u, gb + 2); wy[3] = __shfl(u, gb + 3);
    wy[4] = __shfl(u, gb + 4); wy[5] = __shfl(u, gb + 5);
    wx[0] = __shfl(u, gb + 6); wx[1] = __shfl(u, gb + 7);
    wx[2] = __shfl(v, gb + 0); wx[3] = __shfl(v, gb + 1);
    wx[4] = __shfl(v, gb + 2); wx[5] = __shfl(v, gb + 3);
    float accr0 = 0.f, acci0 = 0.f, accr1 = 0.f, acci1 = 0.f;
    #pragma unroll
    for (int j = 0; j < 6; ++j) {
        float wyj = wy[j];
        #pragma unroll
        for (int p = 0; p < 3; ++p) {
            float w = wyj * wx[2 * p + tp];
            uint2v hu = __builtin_bit_cast(uint2v, h[j * 3 + p]);
            fmamix_lo(accr0, w, hu.x);
            fmamix_hi(acci0, w, hu.x);
            fmamix_lo(accr1, w, hu.y);
            fmamix_hi(acci1, w, hu.y);
        }
    }
    accr0 += __shfl_xor(accr0, 4);
    acci0 += __shfl_xor(acci0, 4);
    accr1 += __shfl_xor(accr1, 4);
    acci1 += __shfl_xor(acci1, 4);
    const float s = 1.0f / (36.0f * GSCALE);
    float2 res = tp ? make_float2(accr1 * s, acci1 * s)
                    : make_float2(accr0 * s, acci0 * s);
    union { float2 f; double d; } ru; ru.f = res;
    __builtin_nontemporal_store(ru.d,
        (double*)(out + (size_t)(2 * cp + tp) * K + k));
}

extern "C" void kernel_launch(void* const* d_in, const int* in_sizes, int n_in,
                              void* d_out, int out_size, void* d_ws, size_t ws_size,
                              hipStream_t stream) {
    const float* imr = (const float*)d_in[0];
    const float* imi = (const float*)d_in[1];
    const float* trj = (const float*)d_in[2];
    int K = in_sizes[2] / 2;

    char* ws = (char*)d_ws;
    float2*   buf1  = (float2*)ws;
    char*     gridh = ws + OFF_GRIDH;
    float*    lut   = (float*)(ws + OFF_LUT);
    unsigned* hist  = (unsigned*)(ws + OFF_HIST);
    unsigned* bases = (unsigned*)(ws + OFF_BASES);
    unsigned* cursor= (unsigned*)(ws + OFF_CURSOR);
    float2*   strj  = (float2*)(ws + OFF_STRJ);
    unsigned* rank  = (unsigned*)(ws + OFF_RANK);
    char*     tmpb  = ws + OFF_TMP;

    (void)n_in; (void)out_size;

    build_lut<<<5, 256, 0, stream>>>(lut, hist);
    dft_pass1<<<dim3(IMN, 4), 320, 0, stream>>>(imr, imi, buf1);
    dft_pass2<<<dim3(OS, 4), 320, 0, stream>>>(buf1, gridh);

    if (ws_size >= WS_NEEDED) {
        hist_kernel<<<512, 256, 0, stream>>>(trj, hist, K);
        scan_kernel<<<1, 512, 0, stream>>>(hist, bases, cursor);
        scatter_kernel<<<(K + 2047) / 2048, 256, 0, stream>>>(trj, cursor, strj, rank, K);
        interp_binned<<<NBINS * NCHUNK, 256, 0, stream>>>(strj, gridh, lut, bases, tmpb);
        permute_out<<<(K + 255) / 256, 256, 0, stream>>>(rank, tmpb, (float2*)d_out, K);
    } else {
        interp_unbinned<<<(K * NCOIL + 255) / 256, 256, 0, stream>>>(trj, gridh, lut,
                                                                     (float2*)d_out, K);
    }
}

// Round 12
// 132.047 us; speedup vs baseline: 3.8274x; 1.9149x over previous
//
#include <hip/hip_runtime.h>
#include <math.h>

#define OS    320      // oversampled grid (ceil(1.25*256))
#define IMN   256
#define NCOIL 8
#define HS    326      // halo grid dim (3-cell wrap halo each side)
#define HROWB (HS * 32)   // halo row stride in bytes (cell = 32B)
#define PI_F  3.14159265358979f
#define BETA_F 10.955108f   // pi*sqrt((4.8*0.75)^2 - 0.8)
#define GSCALE 65536.0f     // fp16 grid scaling

typedef _Float16 half4  __attribute__((ext_vector_type(4)));
typedef unsigned uint2v __attribute__((ext_vector_type(2)));

// f32 acc += f32 w * f16 (lo/hi half of dword h)   [validated r6/r8]
__device__ __forceinline__ void fmamix_lo(float& acc, float w, unsigned h) {
    asm("v_fma_mix_f32 %0, %1, %2, %0 op_sel_hi:[0,1,0]"
        : "+v"(acc) : "v"(w), "v"(h));
}
__device__ __forceinline__ void fmamix_hi(float& acc, float w, unsigned h) {
    asm("v_fma_mix_f32 %0, %1, %2, %0 op_sel:[0,1,0] op_sel_hi:[0,1,0]"
        : "+v"(acc) : "v"(w), "v"(h));
}

// ---- Kaiser-Bessel: exact A&S I0 polynomial (matches reference) ----
__device__ __forceinline__ float i0f(float x) {
    if (x < 3.75f) {
        float y = x * (1.0f / 3.75f); y *= y;
        return 1.0f + y*(3.5156229f + y*(3.0899424f + y*(1.2067492f
             + y*(0.2659732f + y*(0.0360768f + y*0.0045813f)))));
    } else {
        float t = 3.75f / x;
        float p = 0.39894228f + t*(0.01328592f + t*(0.00225319f + t*(-0.00157565f
              + t*(0.00916281f + t*(-0.02057706f + t*(0.02635537f + t*(-0.01647633f
              + t*0.00392377f)))))));
        return expf(x) * rsqrtf(x) * p;
    }
}

__device__ __forceinline__ float apod1(int i) {
    float idx = (float)(i - 128);
    float c = PI_F * 6.0f * idx * (1.0f / (float)OS);
    float a = sqrtf(BETA_F * BETA_F - c * c);
    float sh = 0.5f * (expf(a) - expf(-a));
    return a / sh;
}

// ---- K0: weight LUT ----
__global__ void build_lut(float* __restrict__ lut) {
    int i = blockIdx.x * 256 + threadIdx.x;
    if (i <= 1024)
        lut[i] = i0f(BETA_F * sqrtf(1.0f - (float)i * (1.0f / 1024.0f)));
}

// ======== FFT core: 320 = 5 x 64.  n = 5a+b -> 5 radix-2 DIF 64-FFTs  ========
// LDS layout: per (coil c in 0..1, b in 0..4): float2 sub[64] at (c*5+b)*65
// (stride 65 staggers banks). After 6 in-place DIF stages the sub-array is
// bit-reversed: G_b[m] = sub[rev6(m)].  F[k] = sum_b W320^{bk} G_b[k&63].

#define FFT_STAGES(lds, tw64, cc, bb, jj)                                   \
  {                                                                         \
    int base_ = ((cc) * 5 + (bb)) * 65;                                     \
    _Pragma("unroll")                                                       \
    for (int s_ = 0; s_ < 6; ++s_) {                                        \
      int h_ = 32 >> s_;                                                    \
      int i_ = (jj) & (h_ - 1);                                             \
      int p_ = (((jj) >> (5 - s_)) << (6 - s_)) + i_;                       \
      float2 u_ = lds[base_ + p_];                                          \
      float2 v_ = lds[base_ + p_ + h_];                                     \
      float2 w_ = tw64[i_ << s_];                                           \
      lds[base_ + p_] = make_float2(u_.x + v_.x, u_.y + v_.y);              \
      float dx_ = u_.x - v_.x, dy_ = u_.y - v_.y;                           \
      lds[base_ + p_ + h_] =                                                \
          make_float2(dx_ * w_.x - dy_ * w_.y, dx_ * w_.y + dy_ * w_.x);    \
      __syncthreads();                                                      \
    }                                                                       \
  }

// ---- K1: fused apod + pad + FFT along x.  Block=(image row iy, coil pair).
// out: [kx][y][coil] float2, y = (iy+192)%320, row-apod folded at write.
__global__ __launch_bounds__(320) void fft_pass1(const float* __restrict__ imr,
                                                 const float* __restrict__ imi,
                                                 float2* __restrict__ out) {
    __shared__ float2 xg[10 * 65];     // 5200 B
    __shared__ float2 tw64[33];
    int iy = blockIdx.x;
    int c0 = blockIdx.y * 2;
    int t  = threadIdx.x;

    if (t < 33) {
        float ang = (float)t * (-2.0f * PI_F / 64.0f);
        tw64[t] = make_float2(cosf(ang), sinf(ang));
    }
    // stage: slot s = c*320+n; grid col n = (ix+192)%320; zero for n in [128,192)
    for (int s = t; s < 640; s += 320) {
        int c = s >> 8 >> 6;           // s/320 via (s>=320)
        c = (s >= 320) ? 1 : 0;
        int n = s - c * 320;
        int b = n % 5, a = n / 5;
        float2 v = make_float2(0.f, 0.f);
        if (n >= 192 || n < 128) {
            int ix = (n >= 192) ? (n - 192) : (n + 128);
            float ap = apod1(ix);
            int gi = (c0 + c) * (IMN * IMN) + iy * IMN + ix;
            v = make_float2(imr[gi] * ap, imi[gi] * ap);
        }
        xg[(c * 5 + b) * 65 + a] = v;
    }
    __syncthreads();

    {   // 6 DIF stages; t -> (c, b, j)
        int c = t / 160, r = t - c * 160;
        int b = r >> 5, j = r & 31;
        FFT_STAGES(xg, tw64, c, b, j)
    }

    // combine: k = t, both coils
    int k = t;
    int rm = __brev((unsigned)(k & 63)) >> 26;   // rev6
    float ang1 = (float)k * (-2.0f * PI_F / 320.0f);
    float w1r = cosf(ang1), w1i = sinf(ang1);
    float w2r = w1r * w1r - w1i * w1i, w2i = 2.0f * w1r * w1i;
    float w3r = w2r * w1r - w2i * w1i, w3i = w2r * w1i + w2i * w1r;
    float w4r = w2r * w2r - w2i * w2i, w4i = 2.0f * w2r * w2i;
    float ay = apod1(iy) * (1.0f / 256.0f);   // y-apod + /sqrt(ny*nx)
    int y = iy + 192; if (y >= OS) y -= OS;
    float Fr[2], Fi[2];
    #pragma unroll
    for (int c = 0; c < 2; ++c) {
        int base = c * 5 * 65;
        float2 g0 = xg[base + rm];
        float2 g1 = xg[base + 65 + rm];
        float2 g2 = xg[base + 130 + rm];
        float2 g3 = xg[base + 195 + rm];
        float2 g4 = xg[base + 260 + rm];
        float fr = g0.x, fi = g0.y;
        fr += g1.x * w1r - g1.y * w1i;  fi += g1.x * w1i + g1.y * w1r;
        fr += g2.x * w2r - g2.y * w2i;  fi += g2.x * w2i + g2.y * w2r;
        fr += g3.x * w3r - g3.y * w3i;  fi += g3.x * w3i + g3.y * w3r;
        fr += g4.x * w4r - g4.y * w4i;  fi += g4.x * w4i + g4.y * w4r;
        Fr[c] = fr * ay; Fi[c] = fi * ay;
    }
    *(float4*)(out + ((size_t)k * OS + y) * NCOIL + c0) =
        make_float4(Fr[0], Fi[0], Fr[1], Fi[1]);
}

// ---- K2: FFT along y; fp16 HALO grid out, fftshift folded. Block=(kx, cpair)
__global__ __launch_bounds__(320) void fft_pass2(const float2* __restrict__ in,
                                                 char* __restrict__ gbytes) {
    __shared__ float2 xg[10 * 65];
    __shared__ float2 tw64[33];
    int kx = blockIdx.x;
    int c0 = blockIdx.y * 2;
    int t  = threadIdx.x;

    if (t < 33) {
        float ang = (float)t * (-2.0f * PI_F / 64.0f);
        tw64[t] = make_float2(cosf(ang), sinf(ang));
    }
    const float2* row = in + (size_t)kx * OS * NCOIL + c0;
    for (int s = t; s < 640; s += 320) {
        int c = (s >= 320) ? 1 : 0;
        int n = s - c * 320;
        int b = n % 5, a = n / 5;
        float2 v = make_float2(0.f, 0.f);
        if (n >= 192 || n < 128)             // valid (nonzero) grid rows
            v = row[n * NCOIL + c];
        xg[(c * 5 + b) * 65 + a] = v;
    }
    __syncthreads();

    {
        int c = t / 160, r = t - c * 160;
        int b = r >> 5, j = r & 31;
        FFT_STAGES(xg, tw64, c, b, j)
    }

    int k = t;
    int rm = __brev((unsigned)(k & 63)) >> 26;
    float ang1 = (float)k * (-2.0f * PI_F / 320.0f);
    float w1r = cosf(ang1), w1i = sinf(ang1);
    float w2r = w1r * w1r - w1i * w1i, w2i = 2.0f * w1r * w1i;
    float w3r = w2r * w1r - w2i * w1i, w3i = w2r * w1i + w2i * w1r;
    float w4r = w2r * w2r - w2i * w2i, w4i = 2.0f * w2r * w2i;
    float Fr[2], Fi[2];
    #pragma unroll
    for (int c = 0; c < 2; ++c) {
        int base = c * 5 * 65;
        float2 g0 = xg[base + rm];
        float2 g1 = xg[base + 65 + rm];
        float2 g2 = xg[base + 130 + rm];
        float2 g3 = xg[base + 195 + rm];
        float2 g4 = xg[base + 260 + rm];
        float fr = g0.x, fi = g0.y;
        fr += g1.x * w1r - g1.y * w1i;  fi += g1.x * w1i + g1.y * w1r;
        fr += g2.x * w2r - g2.y * w2i;  fi += g2.x * w2i + g2.y * w2r;
        fr += g3.x * w3r - g3.y * w3i;  fi += g3.x * w3i + g3.y * w3r;
        fr += g4.x * w4r - g4.y * w4i;  fi += g4.x * w4i + g4.y * w4r;
        Fr[c] = fr * GSCALE; Fi[c] = fi * GSCALE;
    }
    int r = k + 160;  if (r >= OS) r -= OS;   // fftshift fold (rows)
    int c2 = kx + 160; if (c2 >= OS) c2 -= OS; // fftshift fold (cols)
    half4 hh;
    hh[0] = (_Float16)Fr[0]; hh[1] = (_Float16)Fi[0];
    hh[2] = (_Float16)Fr[1]; hh[3] = (_Float16)Fi[1];
    // halo replication (validated r8): logical (r,c2) -> hy=r+3 (+wrap images)
    int hys[2]; int nhy = 1; hys[0] = r + 3;
    if (r < 3)        hys[nhy++] = r + 323;
    else if (r >= 317) hys[nhy++] = r - 317;
    int hxs[2]; int nhx = 1; hxs[0] = c2 + 3;
    if (c2 < 3)        hxs[nhx++] = c2 + 323;
    else if (c2 >= 317) hxs[nhx++] = c2 - 317;
    for (int a = 0; a < nhy; ++a)
        for (int b = 0; b < nhx; ++b)
            *(half4*)(gbytes + (size_t)hys[a] * HROWB + hxs[b] * 32 + c0 * 4) = hh;
}

// ---- K3: KB 6x6 gather on halo grid (r8 structure, validated ~115us).
// 8 lanes/point = 4 coil-pairs x 2 tap-parities; LUT weights; fma_mix; NT out.
__global__ __launch_bounds__(256) void interp_kernel(const float* __restrict__ trj,
                                                     const char* __restrict__ gbytes,
                                                     const float* __restrict__ lut,
                                                     float2* __restrict__ out, int K) {
    int tid = blockIdx.x * 256 + threadIdx.x;
    int k = tid >> 3;
    int c = tid & 7;
    int cp = c & 3;
    int tp = c >> 2;
    if (k >= K) return;
    float2 tj = ((const float2*)trj)[k];
    float cy = tj.x * 1.25f + 160.0f;
    float cx = tj.y * 1.25f + 160.0f;
    int y0 = (int)ceilf(cy - 3.0f);
    int x0 = (int)ceilf(cx - 3.0f);
    const char* base0 = gbytes + (size_t)(y0 + 3) * HROWB
                      + (x0 + 3) * 32 + cp * 8 + tp * 32;
    half4 h[18];
    #pragma unroll
    for (int j = 0; j < 6; ++j) {
        const char* rb = base0 + j * HROWB;
        #pragma unroll
        for (int p = 0; p < 3; ++p)
            h[j * 3 + p] = *(const half4*)(rb + p * 64);
    }
    float argu = (c < 6) ? ((float)(y0 + c) - cy) * (1.0f / 3.0f)
                         : ((float)(x0 + (c - 6)) - cx) * (1.0f / 3.0f);
    float argv = ((float)(x0 + 2 + cp) - cx) * (1.0f / 3.0f);
    float tu = fminf(argu * argu * 1024.0f, 1023.0f);
    int   iu = (int)tu;  float fu = tu - (float)iu;
    float a0 = lut[iu], a1 = lut[iu + 1];
    float u = fmaf(fu, a1 - a0, a0);
    float tv = fminf(argv * argv * 1024.0f, 1023.0f);
    int   iv = (int)tv;  float fv = tv - (float)iv;
    float b0 = lut[iv], b1 = lut[iv + 1];
    float v = fmaf(fv, b1 - b0, b0);
    int gb = (threadIdx.x & 63) & 56;
    float wy[6], wx[6];
    wy[0] = __shfl(u, gb + 0); wy[1] = __shfl(u, gb + 1);
    wy[2] = __shfl(u, gb + 2); wy[3] = __shfl(u, gb + 3);
    wy[4] = __shfl(u, gb + 4); wy[5] = __shfl(u, gb + 5);
    wx[0] = __shfl(u, gb + 6); wx[1] = __shfl(u, gb + 7);
    wx[2] = __shfl(v, gb + 0); wx[3] = __shfl(v, gb + 1);
    wx[4] = __shfl(v, gb + 2); wx[5] = __shfl(v, gb + 3);
    float accr0 = 0.f, acci0 = 0.f, accr1 = 0.f, acci1 = 0.f;
    #pragma unroll
    for (int j = 0; j < 6; ++j) {
        float wyj = wy[j];
        #pragma unroll
        for (int p = 0; p < 3; ++p) {
            float w = wyj * wx[2 * p + tp];
            uint2v hu = __builtin_bit_cast(uint2v, h[j * 3 + p]);
            fmamix_lo(accr0, w, hu.x);
            fmamix_hi(acci0, w, hu.x);
            fmamix_lo(accr1, w, hu.y);
            fmamix_hi(acci1, w, hu.y);
        }
    }
    accr0 += __shfl_xor(accr0, 4);
    acci0 += __shfl_xor(acci0, 4);
    accr1 += __shfl_xor(accr1, 4);
    acci1 += __shfl_xor(acci1, 4);
    const float s = 1.0f / (36.0f * GSCALE);
    float2 res = tp ? make_float2(accr1 * s, acci1 * s)
                    : make_float2(accr0 * s, acci0 * s);
    union { float2 f; double d; } ru; ru.f = res;
    __builtin_nontemporal_store(ru.d,
        (double*)(out + (size_t)(2 * cp + tp) * K + k));
}

extern "C" void kernel_launch(void* const* d_in, const int* in_sizes, int n_in,
                              void* d_out, int out_size, void* d_ws, size_t ws_size,
                              hipStream_t stream) {
    const float* imr = (const float*)d_in[0];
    const float* imi = (const float*)d_in[1];
    const float* trj = (const float*)d_in[2];
    int K = in_sizes[2] / 2;

    char* ws = (char*)d_ws;
    float2* buf1  = (float2*)ws;                 // [kx][y][coil]  6,553,600 B
    char*   gridh = ws + 6553600;                // halo fp16 grid 3,400,832 B
    float*  lut   = (float*)(ws + 9954432);      // 4,100 B

    (void)n_in; (void)out_size; (void)ws_size;

    build_lut<<<5, 256, 0, stream>>>(lut);
    fft_pass1<<<dim3(IMN, 4), 320, 0, stream>>>(imr, imi, buf1);
    fft_pass2<<<dim3(OS, 4), 320, 0, stream>>>(buf1, gridh);
    interp_kernel<<<(K * NCOIL + 255) / 256, 256, 0, stream>>>(trj, gridh, lut,
                                                               (float2*)d_out, K);
}

// Round 13
// 126.366 us; speedup vs baseline: 3.9995x; 1.0450x over previous
//
#include <hip/hip_runtime.h>
#include <math.h>

#define OS    320      // oversampled grid (ceil(1.25*256))
#define IMN   256
#define NCOIL 8
#define HS    326      // halo grid dim (3-cell wrap halo each side)
#define HROWB (HS * 32)   // halo row stride in bytes (cell = 32B)
#define PI_F  3.14159265358979f
#define BETA_F 10.955108f   // pi*sqrt((4.8*0.75)^2 - 0.8)
#define GSCALE 65536.0f     // fp16 grid scaling

typedef _Float16 half4  __attribute__((ext_vector_type(4)));
typedef unsigned uint2v __attribute__((ext_vector_type(2)));

// f32 acc += f32 w * f16 (lo/hi half of dword h)   [validated r6/r8]
__device__ __forceinline__ void fmamix_lo(float& acc, float w, unsigned h) {
    asm("v_fma_mix_f32 %0, %1, %2, %0 op_sel_hi:[0,1,0]"
        : "+v"(acc) : "v"(w), "v"(h));
}
__device__ __forceinline__ void fmamix_hi(float& acc, float w, unsigned h) {
    asm("v_fma_mix_f32 %0, %1, %2, %0 op_sel:[0,1,0] op_sel_hi:[0,1,0]"
        : "+v"(acc) : "v"(w), "v"(h));
}

// ---- Kaiser-Bessel: exact A&S I0 polynomial (matches reference) ----
__device__ __forceinline__ float i0f(float x) {
    if (x < 3.75f) {
        float y = x * (1.0f / 3.75f); y *= y;
        return 1.0f + y*(3.5156229f + y*(3.0899424f + y*(1.2067492f
             + y*(0.2659732f + y*(0.0360768f + y*0.0045813f)))));
    } else {
        float t = 3.75f / x;
        float p = 0.39894228f + t*(0.01328592f + t*(0.00225319f + t*(-0.00157565f
              + t*(0.00916281f + t*(-0.02057706f + t*(0.02635537f + t*(-0.01647633f
              + t*0.00392377f)))))));
        return expf(x) * rsqrtf(x) * p;
    }
}

__device__ __forceinline__ float apod1(int i) {
    float idx = (float)(i - 128);
    float c = PI_F * 6.0f * idx * (1.0f / (float)OS);
    float a = sqrtf(BETA_F * BETA_F - c * c);
    float sh = 0.5f * (expf(a) - expf(-a));
    return a / sh;
}

// ---- K0: weight LUT ----
__global__ void build_lut(float* __restrict__ lut) {
    int i = blockIdx.x * 256 + threadIdx.x;
    if (i <= 1024)
        lut[i] = i0f(BETA_F * sqrtf(1.0f - (float)i * (1.0f / 1024.0f)));
}

// ======== FFT core: 320 = 5 x 64 (validated r12) ========
#define FFT_STAGES(lds, tw64, cc, bb, jj)                                   \
  {                                                                         \
    int base_ = ((cc) * 5 + (bb)) * 65;                                     \
    _Pragma("unroll")                                                       \
    for (int s_ = 0; s_ < 6; ++s_) {                                        \
      int h_ = 32 >> s_;                                                    \
      int i_ = (jj) & (h_ - 1);                                             \
      int p_ = (((jj) >> (5 - s_)) << (6 - s_)) + i_;                       \
      float2 u_ = lds[base_ + p_];                                          \
      float2 v_ = lds[base_ + p_ + h_];                                     \
      float2 w_ = tw64[i_ << s_];                                           \
      lds[base_ + p_] = make_float2(u_.x + v_.x, u_.y + v_.y);              \
      float dx_ = u_.x - v_.x, dy_ = u_.y - v_.y;                           \
      lds[base_ + p_ + h_] =                                                \
          make_float2(dx_ * w_.x - dy_ * w_.y, dx_ * w_.y + dy_ * w_.x);    \
      __syncthreads();                                                      \
    }                                                                       \
  }

// ---- K1: fused apod + pad + FFT along x (validated r12) ----
__global__ __launch_bounds__(320) void fft_pass1(const float* __restrict__ imr,
                                                 const float* __restrict__ imi,
                                                 float2* __restrict__ out) {
    __shared__ float2 xg[10 * 65];
    __shared__ float2 tw64[33];
    int iy = blockIdx.x;
    int c0 = blockIdx.y * 2;
    int t  = threadIdx.x;

    if (t < 33) {
        float ang = (float)t * (-2.0f * PI_F / 64.0f);
        tw64[t] = make_float2(cosf(ang), sinf(ang));
    }
    for (int s = t; s < 640; s += 320) {
        int c = (s >= 320) ? 1 : 0;
        int n = s - c * 320;
        int b = n % 5, a = n / 5;
        float2 v = make_float2(0.f, 0.f);
        if (n >= 192 || n < 128) {
            int ix = (n >= 192) ? (n - 192) : (n + 128);
            float ap = apod1(ix);
            int gi = (c0 + c) * (IMN * IMN) + iy * IMN + ix;
            v = make_float2(imr[gi] * ap, imi[gi] * ap);
        }
        xg[(c * 5 + b) * 65 + a] = v;
    }
    __syncthreads();

    {
        int c = t / 160, r = t - c * 160;
        int b = r >> 5, j = r & 31;
        FFT_STAGES(xg, tw64, c, b, j)
    }

    int k = t;
    int rm = __brev((unsigned)(k & 63)) >> 26;
    float ang1 = (float)k * (-2.0f * PI_F / 320.0f);
    float w1r = cosf(ang1), w1i = sinf(ang1);
    float w2r = w1r * w1r - w1i * w1i, w2i = 2.0f * w1r * w1i;
    float w3r = w2r * w1r - w2i * w1i, w3i = w2r * w1i + w2i * w1r;
    float w4r = w2r * w2r - w2i * w2i, w4i = 2.0f * w2r * w2i;
    float ay = apod1(iy) * (1.0f / 256.0f);
    int y = iy + 192; if (y >= OS) y -= OS;
    float Fr[2], Fi[2];
    #pragma unroll
    for (int c = 0; c < 2; ++c) {
        int base = c * 5 * 65;
        float2 g0 = xg[base + rm];
        float2 g1 = xg[base + 65 + rm];
        float2 g2 = xg[base + 130 + rm];
        float2 g3 = xg[base + 195 + rm];
        float2 g4 = xg[base + 260 + rm];
        float fr = g0.x, fi = g0.y;
        fr += g1.x * w1r - g1.y * w1i;  fi += g1.x * w1i + g1.y * w1r;
        fr += g2.x * w2r - g2.y * w2i;  fi += g2.x * w2i + g2.y * w2r;
        fr += g3.x * w3r - g3.y * w3i;  fi += g3.x * w3i + g3.y * w3r;
        fr += g4.x * w4r - g4.y * w4i;  fi += g4.x * w4i + g4.y * w4r;
        Fr[c] = fr * ay; Fi[c] = fi * ay;
    }
    *(float4*)(out + ((size_t)k * OS + y) * NCOIL + c0) =
        make_float4(Fr[0], Fi[0], Fr[1], Fi[1]);
}

// ---- K2: FFT along y; fp16 HALO grid out, fftshift folded (validated r12) ----
__global__ __launch_bounds__(320) void fft_pass2(const float2* __restrict__ in,
                                                 char* __restrict__ gbytes) {
    __shared__ float2 xg[10 * 65];
    __shared__ float2 tw64[33];
    int kx = blockIdx.x;
    int c0 = blockIdx.y * 2;
    int t  = threadIdx.x;

    if (t < 33) {
        float ang = (float)t * (-2.0f * PI_F / 64.0f);
        tw64[t] = make_float2(cosf(ang), sinf(ang));
    }
    const float2* row = in + (size_t)kx * OS * NCOIL + c0;
    for (int s = t; s < 640; s += 320) {
        int c = (s >= 320) ? 1 : 0;
        int n = s - c * 320;
        int b = n % 5, a = n / 5;
        float2 v = make_float2(0.f, 0.f);
        if (n >= 192 || n < 128)
            v = row[n * NCOIL + c];
        xg[(c * 5 + b) * 65 + a] = v;
    }
    __syncthreads();

    {
        int c = t / 160, r = t - c * 160;
        int b = r >> 5, j = r & 31;
        FFT_STAGES(xg, tw64, c, b, j)
    }

    int k = t;
    int rm = __brev((unsigned)(k & 63)) >> 26;
    float ang1 = (float)k * (-2.0f * PI_F / 320.0f);
    float w1r = cosf(ang1), w1i = sinf(ang1);
    float w2r = w1r * w1r - w1i * w1i, w2i = 2.0f * w1r * w1i;
    float w3r = w2r * w1r - w2i * w1i, w3i = w2r * w1i + w2i * w1r;
    float w4r = w2r * w2r - w2i * w2i, w4i = 2.0f * w2r * w2i;
    float Fr[2], Fi[2];
    #pragma unroll
    for (int c = 0; c < 2; ++c) {
        int base = c * 5 * 65;
        float2 g0 = xg[base + rm];
        float2 g1 = xg[base + 65 + rm];
        float2 g2 = xg[base + 130 + rm];
        float2 g3 = xg[base + 195 + rm];
        float2 g4 = xg[base + 260 + rm];
        float fr = g0.x, fi = g0.y;
        fr += g1.x * w1r - g1.y * w1i;  fi += g1.x * w1i + g1.y * w1r;
        fr += g2.x * w2r - g2.y * w2i;  fi += g2.x * w2i + g2.y * w2r;
        fr += g3.x * w3r - g3.y * w3i;  fi += g3.x * w3i + g3.y * w3r;
        fr += g4.x * w4r - g4.y * w4i;  fi += g4.x * w4i + g4.y * w4r;
        Fr[c] = fr * GSCALE; Fi[c] = fi * GSCALE;
    }
    int r = k + 160;  if (r >= OS) r -= OS;
    int c2 = kx + 160; if (c2 >= OS) c2 -= OS;
    half4 hh;
    hh[0] = (_Float16)Fr[0]; hh[1] = (_Float16)Fi[0];
    hh[2] = (_Float16)Fr[1]; hh[3] = (_Float16)Fi[1];
    int hys[2]; int nhy = 1; hys[0] = r + 3;
    if (r < 3)        hys[nhy++] = r + 323;
    else if (r >= 317) hys[nhy++] = r - 317;
    int hxs[2]; int nhx = 1; hxs[0] = c2 + 3;
    if (c2 < 3)        hxs[nhx++] = c2 + 323;
    else if (c2 >= 317) hxs[nhx++] = c2 - 317;
    for (int a = 0; a < nhy; ++a)
        for (int b = 0; b < nhx; ++b)
            *(half4*)(gbytes + (size_t)hys[a] * HROWB + hxs[b] * 32 + c0 * 4) = hh;
}

// ---- K3: KB 6x6 gather, 4 lanes/point (16 points/wave). Each lane owns one
// coil pair and loads ALL 36 taps (8B each) up front — sched_barrier pins the
// loads before the weight path, doubling outstanding misses per wave vs r8.
__global__ __launch_bounds__(256) void interp_kernel(const float* __restrict__ trj,
                                                     const char* __restrict__ gbytes,
                                                     const float* __restrict__ lut,
                                                     float2* __restrict__ out, int K) {
    int tid = blockIdx.x * 256 + threadIdx.x;
    int k  = tid >> 2;          // point index
    int cp = tid & 3;           // coil pair (coils 2cp, 2cp+1)
    if (k >= K) return;
    float2 tj = ((const float2*)trj)[k];
    float cy = tj.x * 1.25f + 160.0f;
    float cx = tj.y * 1.25f + 160.0f;
    int y0 = (int)ceilf(cy - 3.0f);
    int x0 = (int)ceilf(cx - 3.0f);
    const char* base0 = gbytes + (size_t)(y0 + 3) * HROWB + (x0 + 3) * 32 + cp * 8;

    // all 36 tap loads issued before any consumption
    half4 h[36];
    #pragma unroll
    for (int j = 0; j < 6; ++j) {
        const char* rb = base0 + j * HROWB;
        #pragma unroll
        for (int l = 0; l < 6; ++l)
            h[j * 6 + l] = *(const half4*)(rb + l * 32);
    }
    __builtin_amdgcn_sched_barrier(0);   // keep loads ahead of weight path

    // 12 weights per point from 3 LUT evals per lane, 4-lane shfl distribute
    float argA = ((float)(y0 + cp) - cy) * (1.0f / 3.0f);           // wy[cp]
    float argB = ((float)(x0 + cp) - cx) * (1.0f / 3.0f);           // wx[cp]
    float argC = (cp < 2) ? ((float)(y0 + 4 + cp) - cy) * (1.0f / 3.0f)   // wy[4+cp]
                          : ((float)(x0 + 2 + cp) - cx) * (1.0f / 3.0f);  // wx[2+cp]
    float tA = fminf(argA * argA * 1024.0f, 1023.0f);
    int   iA = (int)tA;  float fA = tA - (float)iA;
    float uA = fmaf(fA, lut[iA + 1] - lut[iA], lut[iA]);
    float tB = fminf(argB * argB * 1024.0f, 1023.0f);
    int   iB = (int)tB;  float fB = tB - (float)iB;
    float uB = fmaf(fB, lut[iB + 1] - lut[iB], lut[iB]);
    float tC = fminf(argC * argC * 1024.0f, 1023.0f);
    int   iC = (int)tC;  float fC = tC - (float)iC;
    float uC = fmaf(fC, lut[iC + 1] - lut[iC], lut[iC]);

    int gb = (threadIdx.x & 63) & 60;   // 4-lane group base within wave
    float wy[6], wx[6];
    wy[0] = __shfl(uA, gb + 0); wy[1] = __shfl(uA, gb + 1);
    wy[2] = __shfl(uA, gb + 2); wy[3] = __shfl(uA, gb + 3);
    wx[0] = __shfl(uB, gb + 0); wx[1] = __shfl(uB, gb + 1);
    wx[2] = __shfl(uB, gb + 2); wx[3] = __shfl(uB, gb + 3);
    wy[4] = __shfl(uC, gb + 0); wy[5] = __shfl(uC, gb + 1);
    wx[4] = __shfl(uC, gb + 2); wx[5] = __shfl(uC, gb + 3);

    float r0 = 0.f, i0 = 0.f, r1 = 0.f, i1 = 0.f;
    #pragma unroll
    for (int j = 0; j < 6; ++j) {
        float wyj = wy[j];
        #pragma unroll
        for (int l = 0; l < 6; ++l) {
            float w = wyj * wx[l];
            uint2v hu = __builtin_bit_cast(uint2v, h[j * 6 + l]);
            fmamix_lo(r0, w, hu.x);   // coil 2cp   re
            fmamix_hi(i0, w, hu.x);   //            im
            fmamix_lo(r1, w, hu.y);   // coil 2cp+1 re
            fmamix_hi(i1, w, hu.y);
        }
    }
    const float s = 1.0f / (36.0f * GSCALE);
    union { float2 f; double d; } u0, u1;
    u0.f = make_float2(r0 * s, i0 * s);
    u1.f = make_float2(r1 * s, i1 * s);
    __builtin_nontemporal_store(u0.d, (double*)(out + (size_t)(2 * cp) * K + k));
    __builtin_nontemporal_store(u1.d, (double*)(out + (size_t)(2 * cp + 1) * K + k));
}

extern "C" void kernel_launch(void* const* d_in, const int* in_sizes, int n_in,
                              void* d_out, int out_size, void* d_ws, size_t ws_size,
                              hipStream_t stream) {
    const float* imr = (const float*)d_in[0];
    const float* imi = (const float*)d_in[1];
    const float* trj = (const float*)d_in[2];
    int K = in_sizes[2] / 2;

    char* ws = (char*)d_ws;
    float2* buf1  = (float2*)ws;                 // [kx][y][coil]  6,553,600 B
    char*   gridh = ws + 6553600;                // halo fp16 grid 3,400,832 B
    float*  lut   = (float*)(ws + 9954432);      // 4,100 B

    (void)n_in; (void)out_size; (void)ws_size;

    build_lut<<<5, 256, 0, stream>>>(lut);
    fft_pass1<<<dim3(IMN, 4), 320, 0, stream>>>(imr, imi, buf1);
    fft_pass2<<<dim3(OS, 4), 320, 0, stream>>>(buf1, gridh);
    interp_kernel<<<(K * 4 + 255) / 256, 256, 0, stream>>>(trj, gridh, lut,
                                                           (float2*)d_out, K);
}